// Round 1
// baseline (463.051 us; speedup 1.0000x reference)
//
#include <hip/hip_runtime.h>

// SNN forward scan (ArcTan-surrogate LIF, forward = Heaviside).
//   T=2048, B=64, F=512. W is block-diagonal (2x2 blocks, per the model's
//   input_groups construction) -> ff[f] = W[f,f0]*x[f0] + W[f,f0+1]*x[f0+1],
//   f0 = f & ~1. Off-block entries are exact fp32 zeros, so this is bitwise
//   identical to the full dot product.
// Numerics: __fmul_rn/__fadd_rn everywhere to forbid FMA contraction so the
//   rounding sequence matches the numpy fp32 reference bitwise (Heaviside
//   output: one flipped spike = absmax 1.0).

constexpr int T_STEPS = 2048;
constexpr int B_DIM   = 64;
constexpr int F_DIM   = 512;
constexpr int BF      = B_DIM * F_DIM;       // 32768 elements per timestep
constexpr int CHUNK   = 32;                  // t-steps per register buffer
constexpr int NCHUNK  = T_STEPS / CHUNK;     // 64 (even)

__global__ __launch_bounds__(64) void snn_scan_kernel(
    const float* __restrict__ x,
    const float* __restrict__ W,
    const float* __restrict__ leak_i,
    const float* __restrict__ leak_v,
    const float* __restrict__ thresh,
    float* __restrict__ out) {

    const int g = blockIdx.x * 64 + threadIdx.x;   // g = b*F + f
    const int f  = g & (F_DIM - 1);
    const int f0 = f & ~1;

    // 2x2 block weights for this output row f (loop-invariant).
    const float w_even = W[f * F_DIM + f0];        // coeff on x[f0]   (even f)
    const float w_odd  = W[f * F_DIM + f0 + 1];    // coeff on x[f0+1] (odd f)
    const float li = leak_i[f];
    const float lv = leak_v[f];
    const float th = thresh[f];
    const bool  is_even = ((f & 1) == 0);

    float i_s = 0.0f, v_s = 0.0f, z_s = 0.0f;

    const float* xp = x + g;
    float*       op = out + g;

    float bufA[CHUNK], bufB[CHUNK];

    auto load_chunk = [&](const float* p, float (&buf)[CHUNK]) {
        #pragma unroll
        for (int j = 0; j < CHUNK; ++j) buf[j] = p[j * BF];
    };

    auto process_chunk = [&](float (&buf)[CHUNK], float* o) {
        #pragma unroll
        for (int j = 0; j < CHUNK; ++j) {
            const float xo = buf[j];
            const float xpair = __shfl_xor(xo, 1, 64);   // partner f^1 (lane pairs == f pairs)
            const float xa = is_even ? xo : xpair;       // x at even f of the 2x2 block
            const float xb = is_even ? xpair : xo;       // x at odd  f of the 2x2 block
            // ff = W[f,f0]*x[f0] + W[f,f0+1]*x[f0+1]; one term is an exact 0.
            const float ff = __fadd_rn(__fmul_rn(w_even, xa), __fmul_rn(w_odd, xb));
            // i_new = leak_i*i + ff        (separate mul+add rounding, like numpy)
            i_s = __fadd_rn(__fmul_rn(li, i_s), ff);
            // v_new = (leak_v*v)*(1-z) + i_new ; z in {0,1} so *(1-z) is a select
            float vmul = __fmul_rn(lv, v_s);
            vmul = (z_s > 0.0f) ? 0.0f : vmul;
            v_s = __fadd_rn(vmul, i_s);
            // z_new = heaviside(v_new - thresh): sign of fp sub == direct compare
            z_s = (v_s > th) ? 1.0f : 0.0f;
            o[j * BF] = z_s;
        }
    };

    // Software-pipelined: double-buffered CHUNK-deep prefetch, unrolled by 2
    // to keep buffer indices compile-time constant (no scratch spill).
    load_chunk(xp, bufA);
    for (int c = 0; c < NCHUNK; c += 2) {
        load_chunk(xp + (c + 1) * (CHUNK * BF), bufB);   // c+1 < NCHUNK always (NCHUNK even)
        process_chunk(bufA, op + c * (CHUNK * BF));
        if (c + 2 < NCHUNK)
            load_chunk(xp + (c + 2) * (CHUNK * BF), bufA);
        process_chunk(bufB, op + (c + 1) * (CHUNK * BF));
    }
}

extern "C" void kernel_launch(void* const* d_in, const int* in_sizes, int n_in,
                              void* d_out, int out_size, void* d_ws, size_t ws_size,
                              hipStream_t stream) {
    const float* x      = (const float*)d_in[0];
    const float* W      = (const float*)d_in[1];
    const float* leak_i = (const float*)d_in[2];
    const float* leak_v = (const float*)d_in[3];
    const float* thresh = (const float*)d_in[4];
    float* out = (float*)d_out;

    // B*F = 32768 threads; block=64 -> 512 blocks -> 2 waves/CU over 256 CUs.
    snn_scan_kernel<<<dim3(BF / 64), dim3(64), 0, stream>>>(
        x, W, leak_i, leak_v, thresh, out);
}

// Round 2
// 442.359 us; speedup vs baseline: 1.0468x; 1.0468x over previous
//
#include <hip/hip_runtime.h>

// SNN forward scan (LIF, Heaviside forward). T=2048, B=64, F=512.
// W is block-diagonal with 2x2 blocks (model's input_groups construction):
//   ff[f0]   = W[f0,f0]*x[f0]   + W[f0,f0+1]*x[f0+1]
//   ff[f0+1] = W[f0+1,f0]*x[f0] + W[f0+1,f0+1]*x[f0+1]
// All other summands are exact fp32 zeros -> bitwise identical to full dot.
//
// R1 lessons: (1) __launch_bounds__(64) without min-waves let the allocator
// cap VGPRs at 64, evicting the prefetch buffers -> latency-exposed loads at
// 31% HBM. Fix: (64,1) -> full VGPR budget. (2) One thread now owns the whole
// 2x2 block (float2): no per-step shfl, 8B coalesced loads/stores, two
// independent carry chains per thread.
// Numerics: __fmul_rn/__fadd_rn forbid FMA contraction (must match numpy
// rounding bitwise -- Heaviside output, one flipped spike = absmax 1.0).

constexpr int T_STEPS = 2048;
constexpr int B_DIM   = 64;
constexpr int F_DIM   = 512;
constexpr int BF      = B_DIM * F_DIM;       // 32768 elements per timestep
constexpr int NPAIR   = BF / 2;              // 16384 float2 pairs per timestep
constexpr int CHUNK   = 32;                  // t-steps per register buffer
constexpr int NCHUNK  = T_STEPS / CHUNK;     // 64 (even)

__global__ __launch_bounds__(64, 1) void snn_scan_kernel(
    const float* __restrict__ x,
    const float* __restrict__ W,
    const float* __restrict__ leak_i,
    const float* __restrict__ leak_v,
    const float* __restrict__ thresh,
    float* __restrict__ out) {

    const int p  = blockIdx.x * 64 + threadIdx.x;  // pair index: element base 2p
    const int e  = 2 * p;                          // even element's flat index b*F + f0
    const int f0 = e & (F_DIM - 1);                // even feature of the 2x2 block

    // 2x2 block of W for rows f0, f0+1 (loop-invariant).
    const float w00 = W[(f0    ) * F_DIM + f0    ];
    const float w01 = W[(f0    ) * F_DIM + f0 + 1];
    const float w10 = W[(f0 + 1) * F_DIM + f0    ];
    const float w11 = W[(f0 + 1) * F_DIM + f0 + 1];
    const float li0 = leak_i[f0],     li1 = leak_i[f0 + 1];
    const float lv0 = leak_v[f0],     lv1 = leak_v[f0 + 1];
    const float th0 = thresh[f0],     th1 = thresh[f0 + 1];

    float i0 = 0.0f, v0 = 0.0f, z0 = 0.0f;   // even-f neuron state
    float i1 = 0.0f, v1 = 0.0f, z1 = 0.0f;   // odd-f neuron state

    const float2* xp = (const float2*)(x + e);     // stride BF/2 float2 per t
    float2*       op = (float2*)(out + e);

    float2 bufA[CHUNK], bufB[CHUNK];

    auto load_chunk = [&](const float2* ptr, float2 (&buf)[CHUNK]) {
        #pragma unroll
        for (int j = 0; j < CHUNK; ++j) buf[j] = ptr[j * NPAIR];
    };

    auto process_chunk = [&](float2 (&buf)[CHUNK], float2* o) {
        #pragma unroll
        for (int j = 0; j < CHUNK; ++j) {
            const float xe = buf[j].x;
            const float xo = buf[j].y;
            // ff = 2x2 block matvec (each row: mul, mul, add -- same rounding
            // as numpy's dot over [w*xe, w*xo, 0, 0, ...] reduced pairwise? No:
            // numpy reduces left-to-right over nonzero terms w*xe + w*xo, and
            // both orders agree here since later terms are exact zeros.)
            const float ff0 = __fadd_rn(__fmul_rn(w00, xe), __fmul_rn(w01, xo));
            const float ff1 = __fadd_rn(__fmul_rn(w10, xe), __fmul_rn(w11, xo));
            // i_new = leak_i*i + ff
            i0 = __fadd_rn(__fmul_rn(li0, i0), ff0);
            i1 = __fadd_rn(__fmul_rn(li1, i1), ff1);
            // v_new = (leak_v*v)*(1-z) + i_new ; z in {0,1} -> select
            float vm0 = __fmul_rn(lv0, v0);
            float vm1 = __fmul_rn(lv1, v1);
            vm0 = (z0 > 0.0f) ? 0.0f : vm0;
            vm1 = (z1 > 0.0f) ? 0.0f : vm1;
            v0 = __fadd_rn(vm0, i0);
            v1 = __fadd_rn(vm1, i1);
            // z_new = heaviside(v_new - thresh) == (v_new > thresh)
            z0 = (v0 > th0) ? 1.0f : 0.0f;
            z1 = (v1 > th1) ? 1.0f : 0.0f;
            o[j * NPAIR] = make_float2(z0, z1);
        }
    };

    // Double-buffered CHUNK-deep register prefetch, outer loop unrolled by 2
    // so buffer indices stay compile-time constant (no scratch).
    load_chunk(xp, bufA);
    for (int c = 0; c < NCHUNK; c += 2) {
        load_chunk(xp + (c + 1) * (CHUNK * NPAIR), bufB);
        process_chunk(bufA, op + c * (CHUNK * NPAIR));
        if (c + 2 < NCHUNK)
            load_chunk(xp + (c + 2) * (CHUNK * NPAIR), bufA);
        process_chunk(bufB, op + (c + 1) * (CHUNK * NPAIR));
    }
}

extern "C" void kernel_launch(void* const* d_in, const int* in_sizes, int n_in,
                              void* d_out, int out_size, void* d_ws, size_t ws_size,
                              hipStream_t stream) {
    const float* x      = (const float*)d_in[0];
    const float* W      = (const float*)d_in[1];
    const float* leak_i = (const float*)d_in[2];
    const float* leak_v = (const float*)d_in[3];
    const float* thresh = (const float*)d_in[4];
    float* out = (float*)d_out;

    // 16384 pair-threads; block=64 -> 256 blocks -> 1 wave on each of 256 CUs.
    snn_scan_kernel<<<dim3(NPAIR / 64), dim3(64), 0, stream>>>(
        x, W, leak_i, leak_v, thresh, out);
}